// Round 28
// baseline (929.449 us; speedup 1.0000x reference)
//
#include <hip/hip_runtime.h>

#define DEV __device__ __forceinline__

typedef __attribute__((ext_vector_type(8))) short s8v;
typedef __attribute__((ext_vector_type(4))) short s4v;
typedef __attribute__((ext_vector_type(4))) float f4v;
typedef __attribute__((ext_vector_type(2))) unsigned int u2v;

#define BB 2
#define SS 2048
#define EE 1024
#define AA 1024
#define HH 16
#define FF 4096
#define LL 4
#define DHD 64
#define MM (BB*SS)   /* 4096 rows */

DEV float b2f(short s){
  union { unsigned int u; float f; } v; v.u = ((unsigned int)(unsigned short)s) << 16; return v.f;
}
DEV short f2b(float f){
  unsigned int u = __float_as_uint(f);
  unsigned int r = (u + 0x7FFFu + ((u >> 16) & 1u)) >> 16;
  return (short)(unsigned short)r;
}
DEV unsigned int cvtpk(float lo, float hi){
  unsigned int r; asm("v_cvt_pk_bf16_f32 %0, %1, %2" : "=v"(r) : "v"(lo), "v"(hi)); return r;
}
DEV float vexp2(float x){ float r; asm("v_exp_f32 %0, %1" : "=v"(r) : "v"(x)); return r; }
DEV void gld16(const void* g, void* l){
  __builtin_amdgcn_global_load_lds((const __attribute__((address_space(1))) unsigned int*)g,
                                   (__attribute__((address_space(3))) unsigned int*)l,
                                   16, 0, 0);
}
DEV f4v fzero(){ f4v v; v[0]=0.f; v[1]=0.f; v[2]=0.f; v[3]=0.f; return v; }
// XOR swizzle for [64][64] bf16 LDS tiles (short-index), attention only.
DEV int swz64(int row, int col){ return row*64 + (col ^ ((row&7)<<3)); }

// ---------------- add positional encoding: xb = bf16(x + pe) ----------------
__global__ __launch_bounds__(256) void add_pe_k(const float* __restrict__ x, const float* __restrict__ pe,
                                                short* __restrict__ xb){
  size_t g = ((size_t)blockIdx.x*256 + threadIdx.x) * 4;
  f4v xv = *(const f4v*)(x + g);
  f4v pv = *(const f4v*)(pe + (g & (size_t)(SS*EE - 1)));
  s4v ob;
  #pragma unroll
  for (int j=0;j<4;j++) ob[j] = f2b(xv[j] + pv[j]);
  *(s4v*)(xb + g) = ob;
}

// ---------------- batched transpose+convert: in[z][R][C] (f32) -> out[z][C][R] (bf16) ----------------
__global__ __launch_bounds__(256) void transpose_f2b(const float* __restrict__ in, short* __restrict__ out,
                                                     int R, int C){
  __shared__ short t[32][36];
  int tx = threadIdx.x, ty = threadIdx.y;   // tx:0..7, ty:0..31
  int rt = blockIdx.y*32, ct = blockIdx.x*32;
  size_t zb = (size_t)blockIdx.z * R * C;
  f4v v = *(const f4v*)(in + zb + (size_t)(rt+ty)*C + ct + tx*4);
  #pragma unroll
  for (int j=0;j<4;j++) t[tx*4+j][ty] = f2b(v[j]);
  __syncthreads();
  s4v ov;
  #pragma unroll
  for (int j=0;j<4;j++) ov[j] = t[ty][tx*4+j];
  *(s4v*)(out + zb + (size_t)(ct+ty)*R + rt + tx*4) = ov;
}

// ---------------- fused QKV weight transpose: W{q,k,v}[z][E][DH] -> out[(sel*16+z)][DH][E] ------
__global__ __launch_bounds__(256) void transpose_qkv(const float* __restrict__ Wq, const float* __restrict__ Wk,
                                                     const float* __restrict__ Wv, short* __restrict__ out){
  __shared__ short t[32][36];
  int tx = threadIdx.x, ty = threadIdx.y;   // tx:0..7, ty:0..31
  int rt = blockIdx.y*32, ct = blockIdx.x*32;
  int z = blockIdx.z;                        // 0..47: sel = z/16, head = z%16
  const float* in = (z < 16 ? Wq : (z < 32 ? Wk : Wv));
  size_t zb = (size_t)(z & 15) * EE * DHD;
  f4v v = *(const f4v*)(in + zb + (size_t)(rt+ty)*DHD + ct + tx*4);
  #pragma unroll
  for (int j=0;j<4;j++) t[tx*4+j][ty] = f2b(v[j]);
  __syncthreads();
  s4v ov;
  #pragma unroll
  for (int j=0;j<4;j++) ov[j] = t[ty][tx*4+j];
  *(s4v*)(out + (size_t)z*DHD*EE + (size_t)(ct+ty)*EE + rt + tx*4) = ov;
}

// ---------------- concat qkv biases, all layers in one launch ----------------
__global__ void concat_bias_all(const float* __restrict__ bq, const float* __restrict__ bk,
                                const float* __restrict__ bv, float* __restrict__ out){
  int i = blockIdx.x*256 + threadIdx.x;        // i over LL*3*AA
  int l = i / (3*AA);
  int r = i - l*3*AA;
  float v = (r < AA) ? bq[l*AA + r] : (r < 2*AA ? bk[l*AA + r-AA] : bv[l*AA + r-2*AA]);
  out[i] = v;
}

// ---------------- GEMM BMxBN (2-phase dbuf): QKV(128², OUTMODE=2 V-fuse) / o-proj(64x128) -------
// OUTMODE 0: bf16 out.  OUTMODE 2: QKV mode — V tiles (bn >= 2A) write transposed into Vt.
template<int BM, int BN, int OUTMODE>
__global__ __launch_bounds__(256) void gemm_bt(const short* __restrict__ Ag, const short* __restrict__ Btg,
                                               const float* __restrict__ bias, short* __restrict__ Cout,
                                               short* __restrict__ Vt,
                                               int M, int N, int K){
  constexpr int WM = BM/2, WN = BN/2;
  constexpr int MI = WM/16, NI = WN/16;
  constexpr int ACH = BM/16, BCH = BN/16, TCH = ACH + BCH, CPW = TCH/4;
  __shared__ __attribute__((aligned(16))) short As[2][BM*32];
  __shared__ __attribute__((aligned(16))) short Bs[2][BN*32];
  const int tid = threadIdx.x;
  const int wave = tid >> 6, lane = tid & 63;
  const int wr = wave >> 1, wc = wave & 1;
  const int l15 = lane & 15, l4 = lane >> 4;

  const int gx = gridDim.x;
  const int nwg = gx * gridDim.y;
  const int w0 = blockIdx.y * gx + blockIdx.x;
  const int q8 = nwg >> 3, r8 = nwg & 7;
  const int xcd = w0 & 7, pos = w0 >> 3;
  const int lg = (xcd < r8 ? xcd*(q8+1) : r8*(q8+1) + (xcd-r8)*q8) + pos;
  const int bn = (lg % gx) * BN, bm = (lg / gx) * BM;

  const int lrow = lane >> 2;
  const int lcol = ((lane & 3) ^ ((lane >> 3) & 3)) * 8;
  const int fslot = (l4 ^ ((l15 >> 1) & 3)) * 8;

  f4v acc[MI][NI];
  #pragma unroll
  for (int i=0;i<MI;i++)
    #pragma unroll
    for (int j=0;j<NI;j++) acc[i][j] = fzero();

#define STAGE_TILE(pb, kt) \
  { _Pragma("unroll") \
    for (int c = 0; c < CPW; c++){ \
      int ch = wave * CPW + c; \
      if (ch < ACH){ \
        gld16(Ag + (size_t)(bm + ch*16 + lrow)*K + (kt) + lcol, &As[pb][ch*512]); \
      } else { \
        gld16(Btg + (size_t)(bn + (ch-ACH)*16 + lrow)*K + (kt) + lcol, &Bs[pb][(ch-ACH)*512]); \
      } \
    } }

#define COMPUTE_TILE(pb) \
  { s8v af[MI], bfr[NI]; \
    _Pragma("unroll") \
    for (int mi=0;mi<MI;mi++) af[mi] = *(const s8v*)&As[pb][(wr*WM + mi*16 + l15)*32 + fslot]; \
    _Pragma("unroll") \
    for (int ni=0;ni<NI;ni++) bfr[ni] = *(const s8v*)&Bs[pb][(wc*WN + ni*16 + l15)*32 + fslot]; \
    _Pragma("unroll") \
    for (int mi=0;mi<MI;mi++) \
      _Pragma("unroll") \
      for (int ni=0;ni<NI;ni++) \
        acc[mi][ni] = __builtin_amdgcn_mfma_f32_16x16x32_bf16(af[mi], bfr[ni], acc[mi][ni], 0,0,0); }

  STAGE_TILE(0, 0);
  __syncthreads();
  int cur = 0;
  for (int kt = 32; kt < K; kt += 32){
    STAGE_TILE(cur^1, kt);
    COMPUTE_TILE(cur);
    __syncthreads();
    cur ^= 1;
  }
  COMPUTE_TILE(cur);

#undef STAGE_TILE
#undef COMPUTE_TILE

  if (OUTMODE == 2 && bn >= 2*AA){
    // V tiles: write transposed into Vt[bh][d][t]; t = row..row+3 contiguous -> packed s4v.
    #pragma unroll
    for (int mi=0;mi<MI;mi++){
      int row = bm + wr*WM + mi*16 + l4*4;
      int b = row >> 11, t = row & (SS-1);
      #pragma unroll
      for (int ni=0;ni<NI;ni++){
        int col = bn + wc*WN + ni*16 + l15;
        int vcol = col - 2*AA;
        int bh = b*16 + (vcol >> 6);
        int dl = vcol & 63;
        float bv = bias[col];
        s4v q;
        #pragma unroll
        for (int r=0;r<4;r++) q[r] = f2b(acc[mi][ni][r] + bv);
        *(s4v*)&Vt[((size_t)bh*64 + dl)*SS + t] = q;
      }
    }
  } else {
    #pragma unroll
    for (int mi=0;mi<MI;mi++){
      int row = bm + wr*WM + mi*16 + l4*4;
      #pragma unroll
      for (int ni=0;ni<NI;ni++){
        int col = bn + wc*WN + ni*16 + l15;
        float bv = bias[col];
        #pragma unroll
        for (int r=0;r<4;r++){
          float v = acc[mi][ni][r] + bv;
          Cout[(size_t)(row+r)*N + col] = f2b(v);
        }
      }
    }
  }
}

// ---------------- GEMM 256x256 8-phase: BK=64 as 2x32-k halves, 4-slot ring, depth-3 ----------
// SPLITK=1: plain (FFN1).  SPLITK=4: FFN2 slices kz=0..3 of K/4; partials kz<3 -> Cout+kz*M*N,
// kz==3 -> Calt; bias only in slice 0.
template<int OUTMODE, int SPLITK>
__global__ __launch_bounds__(512) void gemm8p(const short* __restrict__ Ag0, const short* __restrict__ Btg0,
                                              const float* __restrict__ bias, short* __restrict__ Cout0,
                                              short* __restrict__ Calt, int M, int N, int Kfull){
  __shared__ __attribute__((aligned(16))) short Ls[4][2][256*32];   // 128 KiB
  const int tid = threadIdx.x;
  const int wave = tid >> 6, lane = tid & 63;
  const int wm = wave >> 2, wn = wave & 3;      // 2 x 4 waves, per-wave out 128x64
  const int l15 = lane & 15, l4 = lane >> 4;

  const int kz = (SPLITK > 1) ? blockIdx.z : 0;
  const int Kin = Kfull / SPLITK;
  const short* Ag  = Ag0  + (size_t)kz * Kin;
  const short* Btg = Btg0 + (size_t)kz * Kin;
  short* Cout = (SPLITK > 1 && kz == SPLITK-1) ? Calt : (Cout0 + (size_t)kz * M * N);

  const int gx = gridDim.x;
  const int nwg = gx * gridDim.y;
  const int w0 = blockIdx.y * gx + blockIdx.x;
  const int q8 = nwg >> 3, r8 = nwg & 7;
  const int xcd = w0 & 7, pos = w0 >> 3;
  const int lg = (xcd < r8 ? xcd*(q8+1) : r8*(q8+1) + (xcd-r8)*q8) + pos;
  const int bn = (lg % gx) * 256, bm = (lg / gx) * 256;

  const int srow0 = lane >> 2;                  // 0..15 within wave-chunk
  const int fs8 = (l4 ^ (l15 & 3)) * 8;         // swizzled 16B slot (short idx)

  f4v acc[8][4];
  #pragma unroll
  for (int i=0;i<8;i++)
    #pragma unroll
    for (int j=0;j<4;j++) acc[i][j] = fzero();

#define STG(h) { int ss = (h)&3; \
    _Pragma("unroll") \
    for (int i=0;i<2;i++){ \
      int wc = i*8 + wave; \
      int row = wc*16 + srow0; \
      int ls = (lane & 3) ^ (row & 3); \
      gld16(Ag + (size_t)(bm + row)*Kfull + (size_t)(h)*32 + ls*8, &Ls[ss][0][wc*512]); \
      gld16(Btg + (size_t)(bn + row)*Kfull + (size_t)(h)*32 + ls*8, &Ls[ss][1][wc*512]); \
    } }

  const int H = Kin >> 5;                       // number of 32-k half-phases
  STG(0); STG(1); STG(2);
  for (int h = 0; h < H; ++h){
    if (h+2 < H)      asm volatile("s_waitcnt vmcnt(8)\n\ts_barrier" ::: "memory");
    else if (h+1 < H) asm volatile("s_waitcnt vmcnt(4)\n\ts_barrier" ::: "memory");
    else              asm volatile("s_waitcnt vmcnt(0)\n\ts_barrier" ::: "memory");
    if (h+3 < H) STG(h+3);
    const int ss = h&3;
    s8v bf[4], af[8];
    #pragma unroll
    for (int ni=0;ni<4;ni++) bf[ni] = *(const s8v*)&Ls[ss][1][(wn*64 + ni*16 + l15)*32 + fs8];
    #pragma unroll
    for (int mi=0;mi<8;mi++) af[mi] = *(const s8v*)&Ls[ss][0][(wm*128 + mi*16 + l15)*32 + fs8];
    __builtin_amdgcn_s_setprio(1);
    #pragma unroll
    for (int mi=0;mi<8;mi++)
      #pragma unroll
      for (int ni=0;ni<4;ni++)
        acc[mi][ni] = __builtin_amdgcn_mfma_f32_16x16x32_bf16(af[mi], bf[ni], acc[mi][ni], 0,0,0);
    __builtin_amdgcn_s_setprio(0);
  }
#undef STG

  #pragma unroll
  for (int mi=0;mi<8;mi++){
    int row = bm + wm*128 + mi*16 + l4*4;
    #pragma unroll
    for (int ni=0;ni<4;ni++){
      int col = bn + wn*64 + ni*16 + l15;
      float bv = (kz == 0) ? bias[col] : 0.f;
      #pragma unroll
      for (int r=0;r<4;r++){
        float v = acc[mi][ni][r] + bv;
        if constexpr (OUTMODE==1) v = fmaxf(v, 0.f);
        Cout[(size_t)(row+r)*N + col] = f2b(v);
      }
    }
  }
}

// ---------------- flash attention: QBLK=128, 8 waves, K+V double-buffered, 1 barrier/tile ------
__global__ __launch_bounds__(512) void attn_k(const short* __restrict__ qkv, const short* __restrict__ Vt,
                                              short* __restrict__ o){
  __shared__ __attribute__((aligned(16))) short Kls[2][64*64];
  __shared__ __attribute__((aligned(16))) short Vls[2][64*64];
  __shared__ __attribute__((aligned(16))) short Pls[8][16][68];
  const int tid = threadIdx.x, wave = tid>>6, lane = tid&63;
  const int l15 = lane&15, l4 = lane>>4;
  const int w0 = blockIdx.y*16 + blockIdx.x;   // gridDim.x = SS/128 = 16
  const int idx = w0 >> 3;                      // 0..63
  const int bh = (w0 & 7)*4 + (idx >> 4);       // 4 bh per XCD
  const int qb = idx & 15;
  const int b = bh >> 4, h = bh & 15;
  const size_t rs = 3*AA;
  const short* qbase = qkv + (size_t)b*SS*rs + h*64;
  const short* kbase = qbase + AA;
  const short* vtb   = Vt + (size_t)bh*64*SS;
  const int m0 = qb*128 + wave*16;

  const float QSC = 0.125f * 1.44269504f;
  s8v aq0 = *(const s8v*)(qbase + (size_t)(m0 + l15)*rs + l4*8);
  s8v aq1 = *(const s8v*)(qbase + (size_t)(m0 + l15)*rs + 32 + l4*8);
  #pragma unroll
  for (int j=0;j<8;j++){ aq0[j] = f2b(b2f(aq0[j])*QSC); aq1[j] = f2b(b2f(aq1[j])*QSC); }

  f4v oacc[4];
  #pragma unroll
  for (int df=0;df<4;df++) oacc[df] = fzero();
  float lrow = 0.f;

  const int srow = tid >> 3, scol = (tid & 7) * 8;
  s8v kst, vst;

#define LOADKV(t0) \
  kst = *(const s8v*)(kbase + (size_t)((t0)+srow)*rs + scol); \
  vst = *(const s8v*)(vtb + (size_t)srow*SS + (t0) + scol);
#define WRITEKV(pb) \
  *(s8v*)&Kls[pb][swz64(srow, scol)] = kst; \
  *(s8v*)&Vls[pb][swz64(srow, scol)] = vst;

  LOADKV(0); WRITEKV(0);
  __syncthreads();

  for (int t0=0; t0<SS; t0+=64){
    const int cur = (t0>>6)&1;
    const bool more = (t0+64 < SS);
    if (more){ LOADKV(t0+64); }

    f4v sacc[4];
    #pragma unroll
    for (int f=0; f<4; f++){
      s8v k0 = *(const s8v*)&Kls[cur][swz64(f*16+l15, l4*8)];
      s8v k1 = *(const s8v*)&Kls[cur][swz64(f*16+l15, 32+l4*8)];
      f4v s = fzero();
      s = __builtin_amdgcn_mfma_f32_16x16x32_bf16(k0, aq0, s, 0,0,0);
      sacc[f] = __builtin_amdgcn_mfma_f32_16x16x32_bf16(k1, aq1, s, 0,0,0);
    }
    if (more){ WRITEKV(cur^1); }     // overlaps softmax + PV; nobody reads cur^1 this iter

    float rsum = 0.f;
    #pragma unroll
    for (int f=0; f<4; f++){
      #pragma unroll
      for (int r=0; r<4; r++){
        float p = vexp2(sacc[f][r]);
        sacc[f][r] = p; rsum += p;
      }
    }
    rsum += __shfl_xor(rsum, 16);
    rsum += __shfl_xor(rsum, 32);
    lrow += rsum;

    #pragma unroll
    for (int f=0; f<4; f++){
      u2v q;
      q[0] = cvtpk(sacc[f][0], sacc[f][1]);
      q[1] = cvtpk(sacc[f][2], sacc[f][3]);
      *(u2v*)&Pls[wave][l15][f*16 + l4*4] = q;
    }

    s8v ap0 = *(const s8v*)&Pls[wave][l15][l4*8];
    s8v ap1 = *(const s8v*)&Pls[wave][l15][32 + l4*8];
    #pragma unroll
    for (int df=0; df<4; df++){
      s8v v0 = *(const s8v*)&Vls[cur][swz64(df*16+l15, l4*8)];
      s8v v1 = *(const s8v*)&Vls[cur][swz64(df*16+l15, 32+l4*8)];
      oacc[df] = __builtin_amdgcn_mfma_f32_16x16x32_bf16(v0, ap0, oacc[df], 0,0,0);
      oacc[df] = __builtin_amdgcn_mfma_f32_16x16x32_bf16(v1, ap1, oacc[df], 0,0,0);
    }
    __syncthreads();                 // single barrier: writes visible + reads retired
  }
#undef LOADKV
#undef WRITEKV

  float rl = 1.f / lrow;
  short* orow = o + (size_t)(b*SS + m0 + l15)*AA + h*64;
  #pragma unroll
  for (int df=0; df<4; df++){
    u2v q;
    q[0] = cvtpk(oacc[df][0]*rl, oacc[df][1]*rl);
    q[1] = cvtpk(oacc[df][2]*rl, oacc[df][3]*rl);
    *(u2v*)&orow[df*16 + l4*4] = q;
  }
}

// ---------------- fused residual + layernorm (bf16 residual stream) ----------------
template<int MODE>
__global__ __launch_bounds__(256) void ln_fused(const short* __restrict__ y1, const short* __restrict__ y2,
                                                const float* __restrict__ gg, const float* __restrict__ bb,
                                                short* __restrict__ xb, float* __restrict__ fo){
  const int row = blockIdx.x, tid = threadIdx.x;
  size_t base = (size_t)row*EE + tid*4;
  s4v a = *(const s4v*)(y1 + base);
  s4v c = *(const s4v*)(y2 + base);
  f4v y;
  #pragma unroll
  for (int j=0;j<4;j++) y[j] = b2f(a[j]) + b2f(c[j]);
  float s  = y[0]+y[1]+y[2]+y[3];
  float sq = y[0]*y[0]+y[1]*y[1]+y[2]*y[2]+y[3]*y[3];
  #pragma unroll
  for (int msk=1; msk<64; msk<<=1){ s += __shfl_xor(s, msk); sq += __shfl_xor(sq, msk); }
  __shared__ float red[8];
  int wave = tid>>6;
  if ((tid&63)==0){ red[wave]=s; red[4+wave]=sq; }
  __syncthreads();
  s  = red[0]+red[1]+red[2]+red[3];
  sq = red[4]+red[5]+red[6]+red[7];
  float mu  = s * (1.f/EE);
  float var = sq * (1.f/EE) - mu*mu;
  float rstd = rsqrtf(var + 1e-5f);
  f4v ov; s4v ob;
  #pragma unroll
  for (int j=0;j<4;j++){
    int ccol = tid*4 + j;
    float v = (y[j]-mu)*rstd*gg[ccol] + bb[ccol];
    ov[j]=v; ob[j]=f2b(v);
  }
  *(s4v*)(xb + base) = ob;
  if constexpr (MODE==1) *(f4v*)(fo + base) = ov;
}

// ---------------- 5-input residual + LN (4 split-K partials + residual) ----------------
template<int MODE>
__global__ __launch_bounds__(256) void ln_fused4(const short* __restrict__ p0, const short* __restrict__ p1,
                                                 const short* __restrict__ p2, const short* __restrict__ p3,
                                                 const short* __restrict__ y2,
                                                 const float* __restrict__ gg, const float* __restrict__ bb,
                                                 short* __restrict__ xb, float* __restrict__ fo){
  const int row = blockIdx.x, tid = threadIdx.x;
  size_t base = (size_t)row*EE + tid*4;
  s4v a0 = *(const s4v*)(p0 + base);
  s4v a1 = *(const s4v*)(p1 + base);
  s4v a2 = *(const s4v*)(p2 + base);
  s4v a3 = *(const s4v*)(p3 + base);
  s4v c  = *(const s4v*)(y2 + base);
  f4v y;
  #pragma unroll
  for (int j=0;j<4;j++) y[j] = b2f(a0[j]) + b2f(a1[j]) + b2f(a2[j]) + b2f(a3[j]) + b2f(c[j]);
  float s  = y[0]+y[1]+y[2]+y[3];
  float sq = y[0]*y[0]+y[1]*y[1]+y[2]*y[2]+y[3]*y[3];
  #pragma unroll
  for (int msk=1; msk<64; msk<<=1){ s += __shfl_xor(s, msk); sq += __shfl_xor(sq, msk); }
  __shared__ float red[8];
  int wave = tid>>6;
  if ((tid&63)==0){ red[wave]=s; red[4+wave]=sq; }
  __syncthreads();
  s  = red[0]+red[1]+red[2]+red[3];
  sq = red[4]+red[5]+red[6]+red[7];
  float mu  = s * (1.f/EE);
  float var = sq * (1.f/EE) - mu*mu;
  float rstd = rsqrtf(var + 1e-5f);
  f4v ov; s4v ob;
  #pragma unroll
  for (int j=0;j<4;j++){
    int ccol = tid*4 + j;
    float v = (y[j]-mu)*rstd*gg[ccol] + bb[ccol];
    ov[j]=v; ob[j]=f2b(v);
  }
  *(s4v*)(xb + base) = ob;
  if constexpr (MODE==1) *(f4v*)(fo + base) = ov;
}

extern "C" void kernel_launch(void* const* d_in, const int* in_sizes, int n_in,
                              void* d_out, int out_size, void* d_ws, size_t ws_size,
                              hipStream_t stream){
  const float* x   = (const float*)d_in[0];
  const float* pe  = (const float*)d_in[1];
  const float* Wq  = (const float*)d_in[2];
  const float* bq  = (const float*)d_in[3];
  const float* Wk  = (const float*)d_in[4];
  const float* bk  = (const float*)d_in[5];
  const float* Wv  = (const float*)d_in[6];
  const float* bv  = (const float*)d_in[7];
  const float* Wo  = (const float*)d_in[8];
  const float* bo  = (const float*)d_in[9];
  const float* g1  = (const float*)d_in[10];
  const float* be1 = (const float*)d_in[11];
  const float* g2  = (const float*)d_in[12];
  const float* be2 = (const float*)d_in[13];
  const float* W1  = (const float*)d_in[14];
  const float* fb1 = (const float*)d_in[15];
  const float* W2  = (const float*)d_in[16];
  const float* fb2 = (const float*)d_in[17];

  // workspace layout (~80 MB)
  char* wsp = (char*)d_ws;
  short* xb   = (short*)wsp;  wsp += (size_t)MM*EE*2;        //  8 MB
  short* act  = (short*)wsp;  wsp += (size_t)MM*FF*2;        // 32 MB
  short* ob   = (short*)wsp;  wsp += (size_t)MM*AA*2;        //  8 MB (attn out; 4th FFN2 partial)
  short* tmpb = (short*)wsp;  wsp += (size_t)3*MM*EE*2;      // 24 MB (3 split-K partials)
  short* wT   = (short*)wsp;  wsp += (size_t)FF*EE*2;        //  8 MB
  float* bqkv = (float*)wsp;  wsp += (size_t)LL*3*AA*4;      // 48 KB (all layers)
  short* qkv  = act;
  short* Vtb  = act + (size_t)MM*3*AA;
  short* hid  = act;
  short* tmpb1 = tmpb + (size_t)MM*EE;
  short* tmpb2 = tmpb + (size_t)2*MM*EE;

  add_pe_k<<<(MM*EE)/(256*4), 256, 0, stream>>>(x, pe, xb);
  concat_bias_all<<<(LL*3*AA)/256, 256, 0, stream>>>(bq, bk, bv, bqkv);

  dim3 tb2(8,32);
  for (int l=0; l<LL; l++){
    // --- QKV projection (128² 2-phase, V written transposed into Vtb directly) ---
    transpose_qkv<<<dim3(DHD/32, EE/32, 48), tb2, 0, stream>>>(Wq + (size_t)l*HH*EE*DHD,
                                                               Wk + (size_t)l*HH*EE*DHD,
                                                               Wv + (size_t)l*HH*EE*DHD, wT);
    gemm_bt<128,128,2><<<dim3(3*AA/128, MM/128), 256, 0, stream>>>(xb, wT, bqkv + l*3*AA, qkv, Vtb, MM, 3*AA, EE);
    // --- attention (QBLK=128, 8 waves, K+V dbuf, 1 barrier/tile) ---
    attn_k<<<dim3(SS/128, BB*HH), 512, 0, stream>>>(qkv, Vtb, ob);
    // --- output projection (64x128, 512 blocks = 2/CU) + LN1 ---
    transpose_f2b<<<dim3(EE/32, AA/32, 1), tb2, 0, stream>>>(Wo + (size_t)l*AA*EE, wT, AA, EE);
    gemm_bt<64,128,0><<<dim3(EE/128, MM/64), 256, 0, stream>>>(ob, wT, bo + l*EE, tmpb, nullptr, MM, EE, AA);
    ln_fused<0><<<MM, 256, 0, stream>>>(tmpb, xb, g1 + l*EE, be1 + l*EE, xb, nullptr);
    // --- FFN: FFN1 8-phase 256², FFN2 8-phase 256² split-K=4 (256 blocks = 1/CU) ---
    transpose_f2b<<<dim3(FF/32, EE/32, 1), tb2, 0, stream>>>(W1 + (size_t)l*EE*FF, wT, EE, FF);
    gemm8p<1,1><<<dim3(FF/256, MM/256), 512, 0, stream>>>(xb, wT, fb1 + l*FF, hid, nullptr, MM, FF, EE);
    transpose_f2b<<<dim3(EE/32, FF/32, 1), tb2, 0, stream>>>(W2 + (size_t)l*FF*EE, wT, FF, EE);
    gemm8p<0,4><<<dim3(EE/256, MM/256, 4), 512, 0, stream>>>(hid, wT, fb2 + l*EE, tmpb, ob, MM, EE, FF);
    if (l == LL-1)
      ln_fused4<1><<<MM, 256, 0, stream>>>(tmpb, tmpb1, tmpb2, ob, xb, g2 + l*EE, be2 + l*EE, xb, (float*)d_out);
    else
      ln_fused4<0><<<MM, 256, 0, stream>>>(tmpb, tmpb1, tmpb2, ob, xb, g2 + l*EE, be2 + l*EE, xb, nullptr);
  }
}

// Round 29
// 881.962 us; speedup vs baseline: 1.0538x; 1.0538x over previous
//
#include <hip/hip_runtime.h>

#define DEV __device__ __forceinline__

typedef __attribute__((ext_vector_type(8))) short s8v;
typedef __attribute__((ext_vector_type(4))) short s4v;
typedef __attribute__((ext_vector_type(4))) float f4v;
typedef __attribute__((ext_vector_type(2))) unsigned int u2v;

#define BB 2
#define SS 2048
#define EE 1024
#define AA 1024
#define HH 16
#define FF 4096
#define LL 4
#define DHD 64
#define MM (BB*SS)   /* 4096 rows */

DEV float b2f(short s){
  union { unsigned int u; float f; } v; v.u = ((unsigned int)(unsigned short)s) << 16; return v.f;
}
DEV short f2b(float f){
  unsigned int u = __float_as_uint(f);
  unsigned int r = (u + 0x7FFFu + ((u >> 16) & 1u)) >> 16;
  return (short)(unsigned short)r;
}
DEV unsigned int cvtpk(float lo, float hi){
  unsigned int r; asm("v_cvt_pk_bf16_f32 %0, %1, %2" : "=v"(r) : "v"(lo), "v"(hi)); return r;
}
DEV float vexp2(float x){ float r; asm("v_exp_f32 %0, %1" : "=v"(r) : "v"(x)); return r; }
DEV void gld16(const void* g, void* l){
  __builtin_amdgcn_global_load_lds((const __attribute__((address_space(1))) unsigned int*)g,
                                   (__attribute__((address_space(3))) unsigned int*)l,
                                   16, 0, 0);
}
DEV f4v fzero(){ f4v v; v[0]=0.f; v[1]=0.f; v[2]=0.f; v[3]=0.f; return v; }
// XOR swizzle for [64][64] bf16 LDS tiles (short-index), attention only.
DEV int swz64(int row, int col){ return row*64 + (col ^ ((row&7)<<3)); }

// ---------------- add positional encoding: xb = bf16(x + pe) ----------------
__global__ __launch_bounds__(256) void add_pe_k(const float* __restrict__ x, const float* __restrict__ pe,
                                                short* __restrict__ xb){
  size_t g = ((size_t)blockIdx.x*256 + threadIdx.x) * 4;
  f4v xv = *(const f4v*)(x + g);
  f4v pv = *(const f4v*)(pe + (g & (size_t)(SS*EE - 1)));
  s4v ob;
  #pragma unroll
  for (int j=0;j<4;j++) ob[j] = f2b(xv[j] + pv[j]);
  *(s4v*)(xb + g) = ob;
}

// ---------------- batched transpose+convert: in[z][R][C] (f32) -> out[z][C][R] (bf16) ----------------
__global__ __launch_bounds__(256) void transpose_f2b(const float* __restrict__ in, short* __restrict__ out,
                                                     int R, int C){
  __shared__ short t[32][36];
  int tx = threadIdx.x, ty = threadIdx.y;   // tx:0..7, ty:0..31
  int rt = blockIdx.y*32, ct = blockIdx.x*32;
  size_t zb = (size_t)blockIdx.z * R * C;
  f4v v = *(const f4v*)(in + zb + (size_t)(rt+ty)*C + ct + tx*4);
  #pragma unroll
  for (int j=0;j<4;j++) t[tx*4+j][ty] = f2b(v[j]);
  __syncthreads();
  s4v ov;
  #pragma unroll
  for (int j=0;j<4;j++) ov[j] = t[ty][tx*4+j];
  *(s4v*)(out + zb + (size_t)(ct+ty)*R + rt + tx*4) = ov;
}

// ---------------- fused QKV weight transpose: W{q,k,v}[z][E][DH] -> out[(sel*16+z)][DH][E] ------
__global__ __launch_bounds__(256) void transpose_qkv(const float* __restrict__ Wq, const float* __restrict__ Wk,
                                                     const float* __restrict__ Wv, short* __restrict__ out){
  __shared__ short t[32][36];
  int tx = threadIdx.x, ty = threadIdx.y;   // tx:0..7, ty:0..31
  int rt = blockIdx.y*32, ct = blockIdx.x*32;
  int z = blockIdx.z;                        // 0..47: sel = z/16, head = z%16
  const float* in = (z < 16 ? Wq : (z < 32 ? Wk : Wv));
  size_t zb = (size_t)(z & 15) * EE * DHD;
  f4v v = *(const f4v*)(in + zb + (size_t)(rt+ty)*DHD + ct + tx*4);
  #pragma unroll
  for (int j=0;j<4;j++) t[tx*4+j][ty] = f2b(v[j]);
  __syncthreads();
  s4v ov;
  #pragma unroll
  for (int j=0;j<4;j++) ov[j] = t[ty][tx*4+j];
  *(s4v*)(out + (size_t)z*DHD*EE + (size_t)(ct+ty)*EE + rt + tx*4) = ov;
}

// ---------------- V pre-transpose (vectorized): qkv V-section [t][d] -> Vt[bh][d][t] ----------
__global__ __launch_bounds__(256) void vt_k(const short* __restrict__ qkv, short* __restrict__ Vt){
  __shared__ short t[32][36];
  int tx = threadIdx.x, ty = threadIdx.y;   // tx:0..7, ty:0..31
  int t0 = blockIdx.x*32, d0 = blockIdx.y*32, bh = blockIdx.z;
  int b = bh >> 4, h = bh & 15;
  const short* src = qkv + (size_t)b*SS*3*AA + 2*AA + h*64;
  s4v v = *(const s4v*)(src + (size_t)(t0+ty)*3*AA + d0 + tx*4);
  #pragma unroll
  for (int j=0;j<4;j++) t[tx*4+j][ty] = v[j];
  __syncthreads();
  s4v ov;
  #pragma unroll
  for (int j=0;j<4;j++) ov[j] = t[ty][tx*4+j];
  *(s4v*)(Vt + ((size_t)bh*64 + d0 + ty)*SS + t0 + tx*4) = ov;
}

// ---------------- concat qkv biases, all layers in one launch ----------------
__global__ void concat_bias_all(const float* __restrict__ bq, const float* __restrict__ bk,
                                const float* __restrict__ bv, float* __restrict__ out){
  int i = blockIdx.x*256 + threadIdx.x;        // i over LL*3*AA
  int l = i / (3*AA);
  int r = i - l*3*AA;
  float v = (r < AA) ? bq[l*AA + r] : (r < 2*AA ? bk[l*AA + r-AA] : bv[l*AA + r-2*AA]);
  out[i] = v;
}

// ---------------- GEMM BMxBN (2-phase dbuf): QKV(128²) / o-proj(64x128) ----------
template<int BM, int BN, int OUTMODE>
__global__ __launch_bounds__(256) void gemm_bt(const short* __restrict__ Ag, const short* __restrict__ Btg,
                                               const float* __restrict__ bias, short* __restrict__ Cout,
                                               int M, int N, int K){
  constexpr int WM = BM/2, WN = BN/2;
  constexpr int MI = WM/16, NI = WN/16;
  constexpr int ACH = BM/16, BCH = BN/16, TCH = ACH + BCH, CPW = TCH/4;
  __shared__ __attribute__((aligned(16))) short As[2][BM*32];
  __shared__ __attribute__((aligned(16))) short Bs[2][BN*32];
  const int tid = threadIdx.x;
  const int wave = tid >> 6, lane = tid & 63;
  const int wr = wave >> 1, wc = wave & 1;
  const int l15 = lane & 15, l4 = lane >> 4;

  const int gx = gridDim.x;
  const int nwg = gx * gridDim.y;
  const int w0 = blockIdx.y * gx + blockIdx.x;
  const int q8 = nwg >> 3, r8 = nwg & 7;
  const int xcd = w0 & 7, pos = w0 >> 3;
  const int lg = (xcd < r8 ? xcd*(q8+1) : r8*(q8+1) + (xcd-r8)*q8) + pos;
  const int bn = (lg % gx) * BN, bm = (lg / gx) * BM;

  const int lrow = lane >> 2;
  const int lcol = ((lane & 3) ^ ((lane >> 3) & 3)) * 8;
  const int fslot = (l4 ^ ((l15 >> 1) & 3)) * 8;

  f4v acc[MI][NI];
  #pragma unroll
  for (int i=0;i<MI;i++)
    #pragma unroll
    for (int j=0;j<NI;j++) acc[i][j] = fzero();

#define STAGE_TILE(pb, kt) \
  { _Pragma("unroll") \
    for (int c = 0; c < CPW; c++){ \
      int ch = wave * CPW + c; \
      if (ch < ACH){ \
        gld16(Ag + (size_t)(bm + ch*16 + lrow)*K + (kt) + lcol, &As[pb][ch*512]); \
      } else { \
        gld16(Btg + (size_t)(bn + (ch-ACH)*16 + lrow)*K + (kt) + lcol, &Bs[pb][(ch-ACH)*512]); \
      } \
    } }

#define COMPUTE_TILE(pb) \
  { s8v af[MI], bfr[NI]; \
    _Pragma("unroll") \
    for (int mi=0;mi<MI;mi++) af[mi] = *(const s8v*)&As[pb][(wr*WM + mi*16 + l15)*32 + fslot]; \
    _Pragma("unroll") \
    for (int ni=0;ni<NI;ni++) bfr[ni] = *(const s8v*)&Bs[pb][(wc*WN + ni*16 + l15)*32 + fslot]; \
    _Pragma("unroll") \
    for (int mi=0;mi<MI;mi++) \
      _Pragma("unroll") \
      for (int ni=0;ni<NI;ni++) \
        acc[mi][ni] = __builtin_amdgcn_mfma_f32_16x16x32_bf16(af[mi], bfr[ni], acc[mi][ni], 0,0,0); }

  STAGE_TILE(0, 0);
  __syncthreads();
  int cur = 0;
  for (int kt = 32; kt < K; kt += 32){
    STAGE_TILE(cur^1, kt);
    COMPUTE_TILE(cur);
    __syncthreads();
    cur ^= 1;
  }
  COMPUTE_TILE(cur);

#undef STAGE_TILE
#undef COMPUTE_TILE

  #pragma unroll
  for (int mi=0;mi<MI;mi++){
    int row = bm + wr*WM + mi*16 + l4*4;
    #pragma unroll
    for (int ni=0;ni<NI;ni++){
      int col = bn + wc*WN + ni*16 + l15;
      float bv = bias[col];
      #pragma unroll
      for (int r=0;r<4;r++){
        float v = acc[mi][ni][r] + bv;
        if constexpr (OUTMODE==1) v = fmaxf(v, 0.f);
        Cout[(size_t)(row+r)*N + col] = f2b(v);
      }
    }
  }
}

// ---------------- GEMM 256x256 8-phase: BK=64 as 2x32-k halves, 4-slot ring, depth-3 ----------
// SPLITK=1: plain (FFN1).  SPLITK=4: FFN2 slices kz=0..3 of K/4; partials kz<3 -> Cout+kz*M*N,
// kz==3 -> Calt; bias only in slice 0.
template<int OUTMODE, int SPLITK>
__global__ __launch_bounds__(512) void gemm8p(const short* __restrict__ Ag0, const short* __restrict__ Btg0,
                                              const float* __restrict__ bias, short* __restrict__ Cout0,
                                              short* __restrict__ Calt, int M, int N, int Kfull){
  __shared__ __attribute__((aligned(16))) short Ls[4][2][256*32];   // 128 KiB
  const int tid = threadIdx.x;
  const int wave = tid >> 6, lane = tid & 63;
  const int wm = wave >> 2, wn = wave & 3;      // 2 x 4 waves, per-wave out 128x64
  const int l15 = lane & 15, l4 = lane >> 4;

  const int kz = (SPLITK > 1) ? blockIdx.z : 0;
  const int Kin = Kfull / SPLITK;
  const short* Ag  = Ag0  + (size_t)kz * Kin;
  const short* Btg = Btg0 + (size_t)kz * Kin;
  short* Cout = (SPLITK > 1 && kz == SPLITK-1) ? Calt : (Cout0 + (size_t)kz * M * N);

  const int gx = gridDim.x;
  const int nwg = gx * gridDim.y;
  const int w0 = blockIdx.y * gx + blockIdx.x;
  const int q8 = nwg >> 3, r8 = nwg & 7;
  const int xcd = w0 & 7, pos = w0 >> 3;
  const int lg = (xcd < r8 ? xcd*(q8+1) : r8*(q8+1) + (xcd-r8)*q8) + pos;
  const int bn = (lg % gx) * 256, bm = (lg / gx) * 256;

  const int srow0 = lane >> 2;                  // 0..15 within wave-chunk
  const int fs8 = (l4 ^ (l15 & 3)) * 8;         // swizzled 16B slot (short idx)

  f4v acc[8][4];
  #pragma unroll
  for (int i=0;i<8;i++)
    #pragma unroll
    for (int j=0;j<4;j++) acc[i][j] = fzero();

#define STG(h) { int ss = (h)&3; \
    _Pragma("unroll") \
    for (int i=0;i<2;i++){ \
      int wc = i*8 + wave; \
      int row = wc*16 + srow0; \
      int ls = (lane & 3) ^ (row & 3); \
      gld16(Ag + (size_t)(bm + row)*Kfull + (size_t)(h)*32 + ls*8, &Ls[ss][0][wc*512]); \
      gld16(Btg + (size_t)(bn + row)*Kfull + (size_t)(h)*32 + ls*8, &Ls[ss][1][wc*512]); \
    } }

  const int H = Kin >> 5;                       // number of 32-k half-phases
  STG(0); STG(1); STG(2);
  for (int h = 0; h < H; ++h){
    if (h+2 < H)      asm volatile("s_waitcnt vmcnt(8)\n\ts_barrier" ::: "memory");
    else if (h+1 < H) asm volatile("s_waitcnt vmcnt(4)\n\ts_barrier" ::: "memory");
    else              asm volatile("s_waitcnt vmcnt(0)\n\ts_barrier" ::: "memory");
    if (h+3 < H) STG(h+3);
    const int ss = h&3;
    s8v bf[4], af[8];
    #pragma unroll
    for (int ni=0;ni<4;ni++) bf[ni] = *(const s8v*)&Ls[ss][1][(wn*64 + ni*16 + l15)*32 + fs8];
    #pragma unroll
    for (int mi=0;mi<8;mi++) af[mi] = *(const s8v*)&Ls[ss][0][(wm*128 + mi*16 + l15)*32 + fs8];
    __builtin_amdgcn_s_setprio(1);
    #pragma unroll
    for (int mi=0;mi<8;mi++)
      #pragma unroll
      for (int ni=0;ni<4;ni++)
        acc[mi][ni] = __builtin_amdgcn_mfma_f32_16x16x32_bf16(af[mi], bf[ni], acc[mi][ni], 0,0,0);
    __builtin_amdgcn_s_setprio(0);
  }
#undef STG

  #pragma unroll
  for (int mi=0;mi<8;mi++){
    int row = bm + wm*128 + mi*16 + l4*4;
    #pragma unroll
    for (int ni=0;ni<4;ni++){
      int col = bn + wn*64 + ni*16 + l15;
      float bv = (kz == 0) ? bias[col] : 0.f;
      #pragma unroll
      for (int r=0;r<4;r++){
        float v = acc[mi][ni][r] + bv;
        if constexpr (OUTMODE==1) v = fmaxf(v, 0.f);
        Cout[(size_t)(row+r)*N + col] = f2b(v);
      }
    }
  }
}

// ---------------- flash attention: QBLK=128, 8 waves, K+V double-buffered, 1 barrier/tile ------
// Writes at iter u target buf u^1; reads at iter u from buf u&1. Single end-of-iter barrier:
// (a) iter u writes visible before iter u+1 reads u^1; (b) iter u reads of u&1 done before
// iter u+1 writes u&1. Streaming exp2 softmax (bounded scores).
__global__ __launch_bounds__(512) void attn_k(const short* __restrict__ qkv, const short* __restrict__ Vt,
                                              short* __restrict__ o){
  __shared__ __attribute__((aligned(16))) short Kls[2][64*64];
  __shared__ __attribute__((aligned(16))) short Vls[2][64*64];
  __shared__ __attribute__((aligned(16))) short Pls[8][16][68];
  const int tid = threadIdx.x, wave = tid>>6, lane = tid&63;
  const int l15 = lane&15, l4 = lane>>4;
  const int w0 = blockIdx.y*16 + blockIdx.x;   // gridDim.x = SS/128 = 16
  const int idx = w0 >> 3;                      // 0..63
  const int bh = (w0 & 7)*4 + (idx >> 4);       // 4 bh per XCD
  const int qb = idx & 15;
  const int b = bh >> 4, h = bh & 15;
  const size_t rs = 3*AA;
  const short* qbase = qkv + (size_t)b*SS*rs + h*64;
  const short* kbase = qbase + AA;
  const short* vtb   = Vt + (size_t)bh*64*SS;
  const int m0 = qb*128 + wave*16;

  const float QSC = 0.125f * 1.44269504f;
  s8v aq0 = *(const s8v*)(qbase + (size_t)(m0 + l15)*rs + l4*8);
  s8v aq1 = *(const s8v*)(qbase + (size_t)(m0 + l15)*rs + 32 + l4*8);
  #pragma unroll
  for (int j=0;j<8;j++){ aq0[j] = f2b(b2f(aq0[j])*QSC); aq1[j] = f2b(b2f(aq1[j])*QSC); }

  f4v oacc[4];
  #pragma unroll
  for (int df=0;df<4;df++) oacc[df] = fzero();
  float lrow = 0.f;

  const int srow = tid >> 3, scol = (tid & 7) * 8;
  s8v kst, vst;

#define LOADKV(t0) \
  kst = *(const s8v*)(kbase + (size_t)((t0)+srow)*rs + scol); \
  vst = *(const s8v*)(vtb + (size_t)srow*SS + (t0) + scol);
#define WRITEKV(pb) \
  *(s8v*)&Kls[pb][swz64(srow, scol)] = kst; \
  *(s8v*)&Vls[pb][swz64(srow, scol)] = vst;

  LOADKV(0); WRITEKV(0);
  __syncthreads();

  for (int t0=0; t0<SS; t0+=64){
    const int cur = (t0>>6)&1;
    const bool more = (t0+64 < SS);
    if (more){ LOADKV(t0+64); }

    f4v sacc[4];
    #pragma unroll
    for (int f=0; f<4; f++){
      s8v k0 = *(const s8v*)&Kls[cur][swz64(f*16+l15, l4*8)];
      s8v k1 = *(const s8v*)&Kls[cur][swz64(f*16+l15, 32+l4*8)];
      f4v s = fzero();
      s = __builtin_amdgcn_mfma_f32_16x16x32_bf16(k0, aq0, s, 0,0,0);
      sacc[f] = __builtin_amdgcn_mfma_f32_16x16x32_bf16(k1, aq1, s, 0,0,0);
    }
    if (more){ WRITEKV(cur^1); }     // overlaps softmax + PV; nobody reads cur^1 this iter

    float rsum = 0.f;
    #pragma unroll
    for (int f=0; f<4; f++){
      #pragma unroll
      for (int r=0; r<4; r++){
        float p = vexp2(sacc[f][r]);
        sacc[f][r] = p; rsum += p;
      }
    }
    rsum += __shfl_xor(rsum, 16);
    rsum += __shfl_xor(rsum, 32);
    lrow += rsum;

    #pragma unroll
    for (int f=0; f<4; f++){
      u2v q;
      q[0] = cvtpk(sacc[f][0], sacc[f][1]);
      q[1] = cvtpk(sacc[f][2], sacc[f][3]);
      *(u2v*)&Pls[wave][l15][f*16 + l4*4] = q;
    }

    s8v ap0 = *(const s8v*)&Pls[wave][l15][l4*8];
    s8v ap1 = *(const s8v*)&Pls[wave][l15][32 + l4*8];
    #pragma unroll
    for (int df=0; df<4; df++){
      s8v v0 = *(const s8v*)&Vls[cur][swz64(df*16+l15, l4*8)];
      s8v v1 = *(const s8v*)&Vls[cur][swz64(df*16+l15, 32+l4*8)];
      oacc[df] = __builtin_amdgcn_mfma_f32_16x16x32_bf16(v0, ap0, oacc[df], 0,0,0);
      oacc[df] = __builtin_amdgcn_mfma_f32_16x16x32_bf16(v1, ap1, oacc[df], 0,0,0);
    }
    __syncthreads();                 // single barrier: writes visible + reads retired
  }
#undef LOADKV
#undef WRITEKV

  float rl = 1.f / lrow;
  short* orow = o + (size_t)(b*SS + m0 + l15)*AA + h*64;
  #pragma unroll
  for (int df=0; df<4; df++){
    u2v q;
    q[0] = cvtpk(oacc[df][0]*rl, oacc[df][1]*rl);
    q[1] = cvtpk(oacc[df][2]*rl, oacc[df][3]*rl);
    *(u2v*)&orow[df*16 + l4*4] = q;
  }
}

// ---------------- fused residual + layernorm (bf16 residual stream) ----------------
template<int MODE>
__global__ __launch_bounds__(256) void ln_fused(const short* __restrict__ y1, const short* __restrict__ y2,
                                                const float* __restrict__ gg, const float* __restrict__ bb,
                                                short* __restrict__ xb, float* __restrict__ fo){
  const int row = blockIdx.x, tid = threadIdx.x;
  size_t base = (size_t)row*EE + tid*4;
  s4v a = *(const s4v*)(y1 + base);
  s4v c = *(const s4v*)(y2 + base);
  f4v y;
  #pragma unroll
  for (int j=0;j<4;j++) y[j] = b2f(a[j]) + b2f(c[j]);
  float s  = y[0]+y[1]+y[2]+y[3];
  float sq = y[0]*y[0]+y[1]*y[1]+y[2]*y[2]+y[3]*y[3];
  #pragma unroll
  for (int msk=1; msk<64; msk<<=1){ s += __shfl_xor(s, msk); sq += __shfl_xor(sq, msk); }
  __shared__ float red[8];
  int wave = tid>>6;
  if ((tid&63)==0){ red[wave]=s; red[4+wave]=sq; }
  __syncthreads();
  s  = red[0]+red[1]+red[2]+red[3];
  sq = red[4]+red[5]+red[6]+red[7];
  float mu  = s * (1.f/EE);
  float var = sq * (1.f/EE) - mu*mu;
  float rstd = rsqrtf(var + 1e-5f);
  f4v ov; s4v ob;
  #pragma unroll
  for (int j=0;j<4;j++){
    int ccol = tid*4 + j;
    float v = (y[j]-mu)*rstd*gg[ccol] + bb[ccol];
    ov[j]=v; ob[j]=f2b(v);
  }
  *(s4v*)(xb + base) = ob;
  if constexpr (MODE==1) *(f4v*)(fo + base) = ov;
}

// ---------------- 5-input residual + LN (4 split-K partials + residual) ----------------
template<int MODE>
__global__ __launch_bounds__(256) void ln_fused4(const short* __restrict__ p0, const short* __restrict__ p1,
                                                 const short* __restrict__ p2, const short* __restrict__ p3,
                                                 const short* __restrict__ y2,
                                                 const float* __restrict__ gg, const float* __restrict__ bb,
                                                 short* __restrict__ xb, float* __restrict__ fo){
  const int row = blockIdx.x, tid = threadIdx.x;
  size_t base = (size_t)row*EE + tid*4;
  s4v a0 = *(const s4v*)(p0 + base);
  s4v a1 = *(const s4v*)(p1 + base);
  s4v a2 = *(const s4v*)(p2 + base);
  s4v a3 = *(const s4v*)(p3 + base);
  s4v c  = *(const s4v*)(y2 + base);
  f4v y;
  #pragma unroll
  for (int j=0;j<4;j++) y[j] = b2f(a0[j]) + b2f(a1[j]) + b2f(a2[j]) + b2f(a3[j]) + b2f(c[j]);
  float s  = y[0]+y[1]+y[2]+y[3];
  float sq = y[0]*y[0]+y[1]*y[1]+y[2]*y[2]+y[3]*y[3];
  #pragma unroll
  for (int msk=1; msk<64; msk<<=1){ s += __shfl_xor(s, msk); sq += __shfl_xor(sq, msk); }
  __shared__ float red[8];
  int wave = tid>>6;
  if ((tid&63)==0){ red[wave]=s; red[4+wave]=sq; }
  __syncthreads();
  s  = red[0]+red[1]+red[2]+red[3];
  sq = red[4]+red[5]+red[6]+red[7];
  float mu  = s * (1.f/EE);
  float var = sq * (1.f/EE) - mu*mu;
  float rstd = rsqrtf(var + 1e-5f);
  f4v ov; s4v ob;
  #pragma unroll
  for (int j=0;j<4;j++){
    int ccol = tid*4 + j;
    float v = (y[j]-mu)*rstd*gg[ccol] + bb[ccol];
    ov[j]=v; ob[j]=f2b(v);
  }
  *(s4v*)(xb + base) = ob;
  if constexpr (MODE==1) *(f4v*)(fo + base) = ov;
}

extern "C" void kernel_launch(void* const* d_in, const int* in_sizes, int n_in,
                              void* d_out, int out_size, void* d_ws, size_t ws_size,
                              hipStream_t stream){
  const float* x   = (const float*)d_in[0];
  const float* pe  = (const float*)d_in[1];
  const float* Wq  = (const float*)d_in[2];
  const float* bq  = (const float*)d_in[3];
  const float* Wk  = (const float*)d_in[4];
  const float* bk  = (const float*)d_in[5];
  const float* Wv  = (const float*)d_in[6];
  const float* bv  = (const float*)d_in[7];
  const float* Wo  = (const float*)d_in[8];
  const float* bo  = (const float*)d_in[9];
  const float* g1  = (const float*)d_in[10];
  const float* be1 = (const float*)d_in[11];
  const float* g2  = (const float*)d_in[12];
  const float* be2 = (const float*)d_in[13];
  const float* W1  = (const float*)d_in[14];
  const float* fb1 = (const float*)d_in[15];
  const float* W2  = (const float*)d_in[16];
  const float* fb2 = (const float*)d_in[17];

  // workspace layout (~80 MB)
  char* wsp = (char*)d_ws;
  short* xb   = (short*)wsp;  wsp += (size_t)MM*EE*2;        //  8 MB
  short* act  = (short*)wsp;  wsp += (size_t)MM*FF*2;        // 32 MB
  short* ob   = (short*)wsp;  wsp += (size_t)MM*AA*2;        //  8 MB (attn out; 4th FFN2 partial)
  short* tmpb = (short*)wsp;  wsp += (size_t)3*MM*EE*2;      // 24 MB (3 split-K partials)
  short* wT   = (short*)wsp;  wsp += (size_t)FF*EE*2;        //  8 MB
  float* bqkv = (float*)wsp;  wsp += (size_t)LL*3*AA*4;      // 48 KB (all layers)
  short* qkv  = act;
  short* Vtb  = act + (size_t)MM*3*AA;
  short* hid  = act;
  short* tmpb1 = tmpb + (size_t)MM*EE;
  short* tmpb2 = tmpb + (size_t)2*MM*EE;

  add_pe_k<<<(MM*EE)/(256*4), 256, 0, stream>>>(x, pe, xb);
  concat_bias_all<<<(LL*3*AA)/256, 256, 0, stream>>>(bq, bk, bv, bqkv);

  dim3 tb2(8,32);
  for (int l=0; l<LL; l++){
    // --- QKV projection (128² 2-phase, 768 blocks = 3/CU) ---
    transpose_qkv<<<dim3(DHD/32, EE/32, 48), tb2, 0, stream>>>(Wq + (size_t)l*HH*EE*DHD,
                                                               Wk + (size_t)l*HH*EE*DHD,
                                                               Wv + (size_t)l*HH*EE*DHD, wT);
    gemm_bt<128,128,0><<<dim3(3*AA/128, MM/128), 256, 0, stream>>>(xb, wT, bqkv + l*3*AA, qkv, MM, 3*AA, EE);
    // --- attention (QBLK=128, 8 waves, K+V dbuf, 1 barrier/tile) ---
    vt_k<<<dim3(SS/32, DHD/32, BB*HH), tb2, 0, stream>>>(qkv, Vtb);
    attn_k<<<dim3(SS/128, BB*HH), 512, 0, stream>>>(qkv, Vtb, ob);
    // --- output projection (64x128, 512 blocks = 2/CU) + LN1 ---
    transpose_f2b<<<dim3(EE/32, AA/32, 1), tb2, 0, stream>>>(Wo + (size_t)l*AA*EE, wT, AA, EE);
    gemm_bt<64,128,0><<<dim3(EE/128, MM/64), 256, 0, stream>>>(ob, wT, bo + l*EE, tmpb, MM, EE, AA);
    ln_fused<0><<<MM, 256, 0, stream>>>(tmpb, xb, g1 + l*EE, be1 + l*EE, xb, nullptr);
    // --- FFN: FFN1 8-phase 256², FFN2 8-phase 256² split-K=4 (256 blocks = 1/CU) ---
    transpose_f2b<<<dim3(FF/32, EE/32, 1), tb2, 0, stream>>>(W1 + (size_t)l*EE*FF, wT, EE, FF);
    gemm8p<1,1><<<dim3(FF/256, MM/256), 512, 0, stream>>>(xb, wT, fb1 + l*FF, hid, nullptr, MM, FF, EE);
    transpose_f2b<<<dim3(EE/32, FF/32, 1), tb2, 0, stream>>>(W2 + (size_t)l*FF*EE, wT, FF, EE);
    gemm8p<0,4><<<dim3(EE/256, MM/256, 4), 512, 0, stream>>>(hid, wT, fb2 + l*EE, tmpb, ob, MM, EE, FF);
    if (l == LL-1)
      ln_fused4<1><<<MM, 256, 0, stream>>>(tmpb, tmpb1, tmpb2, ob, xb, g2 + l*EE, be2 + l*EE, xb, (float*)d_out);
    else
      ln_fused4<0><<<MM, 256, 0, stream>>>(tmpb, tmpb1, tmpb2, ob, xb, g2 + l*EE, be2 + l*EE, xb, nullptr);
  }
}